// Round 5
// baseline (43315.973 us; speedup 1.0000x reference)
//
#include <hip/hip_runtime.h>
#include <math.h>

#define Bz 16
#define Tz 1024
#define Ez 768
#define E3 2304
#define Vz 50257
#define NBK 256          // 256 blocks: 128 layer-0, 128 layer-1, 6 columns each
#define LN_EPS 1e-5f
#define VEC (Bz*Ez)      // 12288 floats per h vector
#define EP 772           // padded LDS row stride

__device__ __forceinline__ float dot4acc(float acc, float4 w, float4 h){
  acc = fmaf(w.x,h.x,acc); acc = fmaf(w.y,h.y,acc);
  acc = fmaf(w.z,h.z,acc); acc = fmaf(w.w,h.w,acc);
  return acc;
}
__device__ __forceinline__ float sigm(float x){ return 1.0f/(1.0f+expf(-x)); }

// ---------------------------------------------------------------------------
// Persistent cooperative scan; layer-skewed (L0 computes h0(s), L1 computes
// h1(s-1) in super-step s). Arrive: single-counter fetch_add ACQ_REL (the
// release half publishes this block's h stores). Wait: RELAXED polling (no
// buffer_inv storm!) + ONE acquire load once the target is reached.
// Cross-block h exchange via relaxed agent-scope atomics (cache-bypassing),
// so weights stay L2-resident between steps.
// ---------------------------------------------------------------------------
__global__ __launch_bounds__(256) void gru_scan(
    const int* __restrict__ idx, const float* __restrict__ wte,
    const float* __restrict__ Wih, const float* __restrict__ bih,
    const float* __restrict__ Whh, const float* __restrict__ bhh,
    float* __restrict__ h0g, float* __restrict__ h1g,
    unsigned* __restrict__ cnt)
{
  __shared__ float bufX0[Bz][EP];   // L0: x(t) ping   | L1: h0(t)
  __shared__ float bufX1[Bz][EP];   // L0: x(t) pong   | L1: unused
  __shared__ float bufH [Bz][EP];   // h_prev (own layer)
  __shared__ float gates[36][17];   // [row m][batch]
  __shared__ float biasS[36];

  const int tid = threadIdx.x, bx = blockIdx.x;
  const int L = bx>>7, sub = bx&127, c0 = sub*6;
  const int wv = tid>>6, lane = tid&63, kq = lane&15, bb = lane>>4;

  const float* WihL = Wih + (size_t)L*E3*Ez;
  const float* WhhL = Whh + (size_t)L*E3*Ez;

  // 9 weight-row pointers per wave. m = wv*9+r in [0,36):
  //  m<18 -> Wih rows (input = bufX), m>=18 -> Whh rows (input = bufH)
  const float* wrow[9];
#pragma unroll
  for (int r=0;r<9;r++){
    const int m = wv*9+r, mat = m/18, mm = m%18, g = mm/6, cc = mm-g*6;
    wrow[r] = (mat ? WhhL : WihL) + (size_t)(g*Ez + c0 + cc)*Ez;
  }
  if (tid<36){
    const int mat = tid/18, mm = tid%18, g = mm/6, cc = mm-g*6;
    biasS[tid] = (mat ? bhh : bih)[L*E3 + g*Ez + c0 + cc];
  }

  // preload x(0) for layer 0
  if (L==0){
#pragma unroll
    for (int k4=0;k4<12;k4++){
      const int i4 = tid + (k4<<8);
      const int b = i4/192, c4 = i4 - b*192;
      const int row = idx[b*Tz];
      *(float4*)&bufX0[b][c4<<2] = *(const float4*)(wte + (size_t)row*Ez + (c4<<2));
    }
  }
  __syncthreads();

  for (int s=0; s<=Tz; ++s){
    // ---- grid wait: all blocks finished super-step s-1 ----
    if (s>0){
      if (tid==0){
        const unsigned target = (unsigned)s*NBK;
        while (__hip_atomic_load(cnt, __ATOMIC_RELAXED, __HIP_MEMORY_SCOPE_AGENT) < target)
          __builtin_amdgcn_s_sleep(1);
        // one ordering acquire (bounded: 1 per block per step, not per poll)
        (void)__hip_atomic_load(cnt, __ATOMIC_ACQUIRE, __HIP_MEMORY_SCOPE_AGENT);
      }
      __syncthreads();
    }

    const bool active = (L==0) ? (s<Tz) : (s>0);
    if (active){
      const int t = (L==0) ? s : s-1;

      // ---- stage phase: bypass-read h vectors into LDS ----
      if (L==0){
        if (t==0){
#pragma unroll
          for (int k=0;k<48;k++) bufH[k/3][tid + ((k%3)<<8)] = 0.f;
        } else {
          const float* hp = h0g + (size_t)((s-1)&1)*VEC;
#pragma unroll
          for (int k=0;k<48;k++){
            const float v = __hip_atomic_load(hp + tid + (k<<8),
                              __ATOMIC_RELAXED, __HIP_MEMORY_SCOPE_AGENT);
            bufH[k/3][tid + ((k%3)<<8)] = v;
          }
        }
      } else {
        const float* xp = h0g + (size_t)((s-1)&1)*VEC;   // h0(t)
#pragma unroll
        for (int k=0;k<48;k++){
          const float v = __hip_atomic_load(xp + tid + (k<<8),
                            __ATOMIC_RELAXED, __HIP_MEMORY_SCOPE_AGENT);
          bufX0[k/3][tid + ((k%3)<<8)] = v;
        }
        if (t==0){
#pragma unroll
          for (int k=0;k<48;k++) bufH[k/3][tid + ((k%3)<<8)] = 0.f;
        } else {
          const float* hp = h1g + (size_t)(s&1)*VEC;     // h1(t-1)
#pragma unroll
          for (int k=0;k<48;k++){
            const float v = __hip_atomic_load(hp + tid + (k<<8),
                              __ATOMIC_RELAXED, __HIP_MEMORY_SCOPE_AGENT);
            bufH[k/3][tid + ((k%3)<<8)] = v;
          }
        }
      }
      __syncthreads();

      // ---- matmul: 9 rows/wave x 16 batches, k split 16-way (kq) ----
      const float (*V)[EP];
      if (wv<2) V = (L==0) ? ((s&1) ? bufX1 : bufX0) : bufX0;
      else      V = bufH;

      float acc[9][4];
#pragma unroll
      for (int r=0;r<9;r++)
#pragma unroll
        for (int bi=0;bi<4;bi++) acc[r][bi]=0.f;

#pragma unroll 4
      for (int j=0;j<12;j++){
        const int kk = (j<<6) + (kq<<2);
        float4 wv4[9];
#pragma unroll
        for (int r=0;r<9;r++) wv4[r] = *(const float4*)(wrow[r] + kk);
#pragma unroll
        for (int bi=0;bi<4;bi++){
          const float4 hv = *(const float4*)&V[bb*4+bi][kk];
#pragma unroll
          for (int r=0;r<9;r++) acc[r][bi] = dot4acc(acc[r][bi], wv4[r], hv);
        }
      }
#pragma unroll
      for (int r=0;r<9;r++)
#pragma unroll
        for (int bi=0;bi<4;bi++){
          float a = acc[r][bi];
          a += __shfl_xor(a,1); a += __shfl_xor(a,2);
          a += __shfl_xor(a,4); a += __shfl_xor(a,8);
          acc[r][bi]=a;
        }
      if (kq==0){
#pragma unroll
        for (int r=0;r<9;r++)
#pragma unroll
          for (int bi=0;bi<4;bi++) gates[wv*9+r][bb*4+bi] = acc[r][bi];
      }
      __syncthreads();

      // ---- nonlinearity + publish h-slice (96 threads: 16 b x 6 cols) ----
      if (tid < 96){
        const int b = tid&15, cc = tid>>4;
        const float gir = gates[cc   ][b] + biasS[cc];
        const float giz = gates[6+cc ][b] + biasS[6+cc];
        const float gin = gates[12+cc][b] + biasS[12+cc];
        const float ghr = gates[18+cc][b] + biasS[18+cc];
        const float ghz = gates[24+cc][b] + biasS[24+cc];
        const float ghn = gates[30+cc][b] + biasS[30+cc];
        const float r = sigm(gir+ghr);
        const float z = sigm(giz+ghz);
        const float n = tanhf(fmaf(r, ghn, gin));
        const float hp = bufH[b][c0+cc];
        const float hv = fmaf(z, hp - n, n);
        float* hOut = (L==0) ? (h0g + (size_t)(s&1)*VEC)
                             : (h1g + (size_t)((s-1)&1)*VEC);
        __hip_atomic_store(hOut + b*Ez + c0 + cc, hv,
                           __ATOMIC_RELAXED, __HIP_MEMORY_SCOPE_AGENT);
      }

      // ---- prefetch x(s+1) into the other X buffer (off critical path) ----
      if (L==0 && s+1 < Tz){
        float (*bx_)[EP] = ((s+1)&1) ? bufX1 : bufX0;
#pragma unroll
        for (int k4=0;k4<12;k4++){
          const int i4 = tid + (k4<<8);
          const int b = i4/192, c4 = i4 - b*192;
          const int row = idx[b*Tz + (s+1)];
          *(float4*)&bx_[b][c4<<2] = *(const float4*)(wte + (size_t)row*Ez + (c4<<2));
        }
      }
    }

    // ---- arrive: ACQ_REL fetch_add (release publishes h stores) ----
    __syncthreads();
    if (tid==0)
      __hip_atomic_fetch_add(cnt, 1u, __ATOMIC_ACQ_REL, __HIP_MEMORY_SCOPE_AGENT);
  }
}

// LayerNorm of final h1 -> ln
__global__ __launch_bounds__(256) void finalize_ln(
    const float* __restrict__ h1, const float* __restrict__ g,
    float* __restrict__ ln)
{
  const int tid=threadIdx.x, wv=tid>>6, lane=tid&63;
  for (int b=wv; b<Bz; b+=4){
    float sum=0.f;
    for (int c=lane;c<Ez;c+=64) sum += h1[b*Ez+c];
#pragma unroll
    for (int off=32; off; off>>=1) sum += __shfl_xor(sum, off);
    const float mu = sum/(float)Ez;
    float s2=0.f;
    for (int c=lane;c<Ez;c+=64){ const float d=h1[b*Ez+c]-mu; s2=fmaf(d,d,s2); }
#pragma unroll
    for (int off=32; off; off>>=1) s2 += __shfl_xor(s2, off);
    const float inv = rsqrtf(s2/(float)Ez + LN_EPS);
    for (int c=lane;c<Ez;c+=64) ln[b*Ez+c] = (h1[b*Ez+c]-mu)*inv*g[c];
  }
}

// logits[b,v] = dot(ln[b,:], wte[v,:]) ; 64 rows per block, 16 rows per wave.
__global__ __launch_bounds__(256) void lm_head(
    const float* __restrict__ ln, const float* __restrict__ wte,
    float* __restrict__ out)
{
  __shared__ float sLn[Bz][EP];
  const int tid=threadIdx.x;
  for (int i4=tid; i4<Bz*Ez/4; i4+=256){
    const int b = i4/(Ez/4), c = (i4 - b*(Ez/4))<<2;
    *(float4*)(&sLn[b][c]) = *(const float4*)(ln + b*Ez + c);
  }
  __syncthreads();
  const int wv=tid>>6, lane=tid&63, rr=lane>>4, cl=lane&15;
  const int vbase = blockIdx.x*64 + wv*16 + rr;
  float acc[4][16];
#pragma unroll
  for (int k=0;k<4;k++)
#pragma unroll
    for (int b=0;b<16;b++) acc[k][b]=0.f;

  for (int j=0;j<12;j++){
    const int c = (cl<<2) + (j<<6);
    float4 w4[4];
#pragma unroll
    for (int k=0;k<4;k++){
      const int v = vbase + 4*k;
      if (v < Vz) w4[k] = *(const float4*)(wte + (size_t)v*Ez + c);
      else { w4[k].x=w4[k].y=w4[k].z=w4[k].w=0.f; }
    }
#pragma unroll
    for (int b=0;b<16;b++){
      const float4 hv = *(const float4*)(&sLn[b][c]);
#pragma unroll
      for (int k=0;k<4;k++) acc[k][b] = dot4acc(acc[k][b], w4[k], hv);
    }
  }
#pragma unroll
  for (int off=1; off<16; off<<=1)
#pragma unroll
    for (int k=0;k<4;k++)
#pragma unroll
      for (int b=0;b<16;b++) acc[k][b] += __shfl_xor(acc[k][b], off);

  if (cl==0){
#pragma unroll
    for (int k=0;k<4;k++){
      const int v = vbase + 4*k;
      if (v < Vz){
#pragma unroll
        for (int b=0;b<16;b++) out[(size_t)b*Vz + v] = acc[k][b];
      }
    }
  }
}

extern "C" void kernel_launch(void* const* d_in, const int* in_sizes, int n_in,
                              void* d_out, int out_size, void* d_ws, size_t ws_size,
                              hipStream_t stream) {
  const int*   idx = (const int*)  d_in[0];
  const float* wte = (const float*)d_in[1];
  const float* Wih = (const float*)d_in[2];
  const float* bih = (const float*)d_in[3];
  const float* Whh = (const float*)d_in[4];
  const float* bhh = (const float*)d_in[5];
  const float* g   = (const float*)d_in[6];
  float* out = (float*)d_out;

  float* base = (float*)d_ws;
  unsigned* cnt = (unsigned*)d_ws;           // words [0,64): barrier counter
  float* h0g = base + 64;                    // 2 * B*E
  float* h1g = h0g + 2*VEC;                  // 2 * B*E
  float* ln  = h1g + 2*VEC;                  // B*E

  (void)hipMemsetAsync(d_ws, 0, 256, stream);   // reset barrier each (re)play

  void* args[] = {(void*)&idx,(void*)&wte,(void*)&Wih,(void*)&bih,
                  (void*)&Whh,(void*)&bhh,(void*)&h0g,(void*)&h1g,(void*)&cnt};
  (void)hipLaunchCooperativeKernel((void*)gru_scan, dim3(NBK), dim3(256), args, 0, stream);

  // final h1(1023) lives in h1g[(Tz-1)&1] = h1g + VEC
  finalize_ln<<<1, 256, 0, stream>>>(h1g + VEC, g, ln);
  lm_head<<<786, 256, 0, stream>>>(ln, wte, out);
}

// Round 6
// 33536.975 us; speedup vs baseline: 1.2916x; 1.2916x over previous
//
#include <hip/hip_runtime.h>
#include <math.h>

#define Bz 16
#define Tz 1024
#define Ez 768
#define E3 2304
#define Vz 50257
#define NBK 256          // 256 blocks: 128 layer-0, 128 layer-1, 6 columns each
#define LN_EPS 1e-5f
#define VEC (Bz*Ez)      // 12288 floats per h vector
#define EP 772           // padded LDS row stride

__device__ __forceinline__ float dot4acc(float acc, float4 w, float4 h){
  acc = fmaf(w.x,h.x,acc); acc = fmaf(w.y,h.y,acc);
  acc = fmaf(w.z,h.z,acc); acc = fmaf(w.w,h.w,acc);
  return acc;
}
__device__ __forceinline__ float sigm(float x){ return 1.0f/(1.0f+expf(-x)); }

// ---------------------------------------------------------------------------
// Persistent cooperative scan; layer-skewed (L0 computes h0(s), L1 computes
// h1(s-1) in super-step s). Barrier = R2's proven fully-relaxed protocol,
// but the single counter is split into 32 counters on 32 distinct 128-B
// cache lines (block bx -> counter bx&31): same-line RMW serialization drops
// from 256-deep (~28us) to 8-deep x 32 lines in parallel (~1us).
// Wait: 32 lanes each poll one counter (relaxed) + __all ballot. NO acquire
// anywhere in the loop (R5 measured acquire at +7us/step).
// Cross-block h exchange via relaxed agent-scope atomics; weights stay
// L2-resident between steps.
// ---------------------------------------------------------------------------
__global__ __launch_bounds__(256) void gru_scan(
    const int* __restrict__ idx, const float* __restrict__ wte,
    const float* __restrict__ Wih, const float* __restrict__ bih,
    const float* __restrict__ Whh, const float* __restrict__ bhh,
    float* __restrict__ h0g, float* __restrict__ h1g,
    unsigned* __restrict__ cnt)
{
  __shared__ float bufX0[Bz][EP];   // L0: x(t) ping   | L1: h0(t)
  __shared__ float bufX1[Bz][EP];   // L0: x(t) pong   | L1: unused
  __shared__ float bufH [Bz][EP];   // h_prev (own layer)
  __shared__ float gates[36][17];   // [row m][batch]
  __shared__ float biasS[36];

  const int tid = threadIdx.x, bx = blockIdx.x;
  const int L = bx>>7, sub = bx&127, c0 = sub*6;
  const int wv = tid>>6, lane = tid&63, kq = lane&15, bb = lane>>4;

  const float* WihL = Wih + (size_t)L*E3*Ez;
  const float* WhhL = Whh + (size_t)L*E3*Ez;

  // 9 weight-row pointers per wave. m = wv*9+r in [0,36):
  //  m<18 -> Wih rows (input = bufX), m>=18 -> Whh rows (input = bufH)
  const float* wrow[9];
#pragma unroll
  for (int r=0;r<9;r++){
    const int m = wv*9+r, mat = m/18, mm = m%18, g = mm/6, cc = mm-g*6;
    wrow[r] = (mat ? WhhL : WihL) + (size_t)(g*Ez + c0 + cc)*Ez;
  }
  if (tid<36){
    const int mat = tid/18, mm = tid%18, g = mm/6, cc = mm-g*6;
    biasS[tid] = (mat ? bhh : bih)[L*E3 + g*Ez + c0 + cc];
  }

  // preload x(0) for layer 0
  if (L==0){
#pragma unroll
    for (int k4=0;k4<12;k4++){
      const int i4 = tid + (k4<<8);
      const int b = i4/192, c4 = i4 - b*192;
      const int row = idx[b*Tz];
      *(float4*)&bufX0[b][c4<<2] = *(const float4*)(wte + (size_t)row*Ez + (c4<<2));
    }
  }
  __syncthreads();

  for (int s=0; s<=Tz; ++s){
    // ---- grid wait: all 32 counters reached 8*s (relaxed poll, no acquire) ----
    if (s>0){
      if (tid<32){
        const unsigned tgt = (unsigned)s*8u;
        const unsigned* f = cnt + (tid<<5);       // 32 counters, 128B apart
        for(;;){
          const unsigned v = __hip_atomic_load(f, __ATOMIC_RELAXED, __HIP_MEMORY_SCOPE_AGENT);
          if (__all(v >= tgt)) break;
          __builtin_amdgcn_s_sleep(1);
        }
      }
      __syncthreads();
    }

    const bool active = (L==0) ? (s<Tz) : (s>0);
    if (active){
      const int t = (L==0) ? s : s-1;

      // ---- stage phase: bypass-read h vectors into LDS ----
      if (L==0){
        if (t==0){
#pragma unroll
          for (int k=0;k<48;k++) bufH[k/3][tid + ((k%3)<<8)] = 0.f;
        } else {
          const float* hp = h0g + (size_t)((s-1)&1)*VEC;
#pragma unroll
          for (int k=0;k<48;k++){
            const float v = __hip_atomic_load(hp + tid + (k<<8),
                              __ATOMIC_RELAXED, __HIP_MEMORY_SCOPE_AGENT);
            bufH[k/3][tid + ((k%3)<<8)] = v;
          }
        }
      } else {
        const float* xp = h0g + (size_t)((s-1)&1)*VEC;   // h0(t)
#pragma unroll
        for (int k=0;k<48;k++){
          const float v = __hip_atomic_load(xp + tid + (k<<8),
                            __ATOMIC_RELAXED, __HIP_MEMORY_SCOPE_AGENT);
          bufX0[k/3][tid + ((k%3)<<8)] = v;
        }
        if (t==0){
#pragma unroll
          for (int k=0;k<48;k++) bufH[k/3][tid + ((k%3)<<8)] = 0.f;
        } else {
          const float* hp = h1g + (size_t)(s&1)*VEC;     // h1(t-1)
#pragma unroll
          for (int k=0;k<48;k++){
            const float v = __hip_atomic_load(hp + tid + (k<<8),
                              __ATOMIC_RELAXED, __HIP_MEMORY_SCOPE_AGENT);
            bufH[k/3][tid + ((k%3)<<8)] = v;
          }
        }
      }
      __syncthreads();

      // ---- matmul: 9 rows/wave x 16 batches, k split 16-way (kq) ----
      const float (*V)[EP];
      if (wv<2) V = (L==0) ? ((s&1) ? bufX1 : bufX0) : bufX0;
      else      V = bufH;

      float acc[9][4];
#pragma unroll
      for (int r=0;r<9;r++)
#pragma unroll
        for (int bi=0;bi<4;bi++) acc[r][bi]=0.f;

#pragma unroll 4
      for (int j=0;j<12;j++){
        const int kk = (j<<6) + (kq<<2);
        float4 wv4[9];
#pragma unroll
        for (int r=0;r<9;r++) wv4[r] = *(const float4*)(wrow[r] + kk);
#pragma unroll
        for (int bi=0;bi<4;bi++){
          const float4 hv = *(const float4*)&V[bb*4+bi][kk];
#pragma unroll
          for (int r=0;r<9;r++) acc[r][bi] = dot4acc(acc[r][bi], wv4[r], hv);
        }
      }
#pragma unroll
      for (int r=0;r<9;r++)
#pragma unroll
        for (int bi=0;bi<4;bi++){
          float a = acc[r][bi];
          a += __shfl_xor(a,1); a += __shfl_xor(a,2);
          a += __shfl_xor(a,4); a += __shfl_xor(a,8);
          acc[r][bi]=a;
        }
      if (kq==0){
#pragma unroll
        for (int r=0;r<9;r++)
#pragma unroll
          for (int bi=0;bi<4;bi++) gates[wv*9+r][bb*4+bi] = acc[r][bi];
      }
      __syncthreads();

      // ---- nonlinearity + publish h-slice (96 threads: 16 b x 6 cols) ----
      if (tid < 96){
        const int b = tid&15, cc = tid>>4;
        const float gir = gates[cc   ][b] + biasS[cc];
        const float giz = gates[6+cc ][b] + biasS[6+cc];
        const float gin = gates[12+cc][b] + biasS[12+cc];
        const float ghr = gates[18+cc][b] + biasS[18+cc];
        const float ghz = gates[24+cc][b] + biasS[24+cc];
        const float ghn = gates[30+cc][b] + biasS[30+cc];
        const float r = sigm(gir+ghr);
        const float z = sigm(giz+ghz);
        const float n = tanhf(fmaf(r, ghn, gin));
        const float hp = bufH[b][c0+cc];
        const float hv = fmaf(z, hp - n, n);
        float* hOut = (L==0) ? (h0g + (size_t)(s&1)*VEC)
                             : (h1g + (size_t)((s-1)&1)*VEC);
        __hip_atomic_store(hOut + b*Ez + c0 + cc, hv,
                           __ATOMIC_RELAXED, __HIP_MEMORY_SCOPE_AGENT);
      }

      // ---- prefetch x(s+1) into the other X buffer (off critical path) ----
      if (L==0 && s+1 < Tz){
        float (*bx_)[EP] = ((s+1)&1) ? bufX1 : bufX0;
#pragma unroll
        for (int k4=0;k4<12;k4++){
          const int i4 = tid + (k4<<8);
          const int b = i4/192, c4 = i4 - b*192;
          const int row = idx[b*Tz + (s+1)];
          *(float4*)&bx_[b][c4<<2] = *(const float4*)(wte + (size_t)row*Ez + (c4<<2));
        }
      }
    }

    // ---- arrive: syncthreads drains vmcnt (h stores complete), then
    //      relaxed fetch_add on this block's line (bx&31) ----
    __syncthreads();
    if (tid==0)
      __hip_atomic_fetch_add(cnt + ((bx&31)<<5), 1u,
                             __ATOMIC_RELAXED, __HIP_MEMORY_SCOPE_AGENT);
  }
}

// LayerNorm of final h1 -> ln
__global__ __launch_bounds__(256) void finalize_ln(
    const float* __restrict__ h1, const float* __restrict__ g,
    float* __restrict__ ln)
{
  const int tid=threadIdx.x, wv=tid>>6, lane=tid&63;
  for (int b=wv; b<Bz; b+=4){
    float sum=0.f;
    for (int c=lane;c<Ez;c+=64) sum += h1[b*Ez+c];
#pragma unroll
    for (int off=32; off; off>>=1) sum += __shfl_xor(sum, off);
    const float mu = sum/(float)Ez;
    float s2=0.f;
    for (int c=lane;c<Ez;c+=64){ const float d=h1[b*Ez+c]-mu; s2=fmaf(d,d,s2); }
#pragma unroll
    for (int off=32; off; off>>=1) s2 += __shfl_xor(s2, off);
    const float inv = rsqrtf(s2/(float)Ez + LN_EPS);
    for (int c=lane;c<Ez;c+=64) ln[b*Ez+c] = (h1[b*Ez+c]-mu)*inv*g[c];
  }
}

// logits[b,v] = dot(ln[b,:], wte[v,:]) ; 64 rows per block, 16 rows per wave.
__global__ __launch_bounds__(256) void lm_head(
    const float* __restrict__ ln, const float* __restrict__ wte,
    float* __restrict__ out)
{
  __shared__ float sLn[Bz][EP];
  const int tid=threadIdx.x;
  for (int i4=tid; i4<Bz*Ez/4; i4+=256){
    const int b = i4/(Ez/4), c = (i4 - b*(Ez/4))<<2;
    *(float4*)(&sLn[b][c]) = *(const float4*)(ln + b*Ez + c);
  }
  __syncthreads();
  const int wv=tid>>6, lane=tid&63, rr=lane>>4, cl=lane&15;
  const int vbase = blockIdx.x*64 + wv*16 + rr;
  float acc[4][16];
#pragma unroll
  for (int k=0;k<4;k++)
#pragma unroll
    for (int b=0;b<16;b++) acc[k][b]=0.f;

  for (int j=0;j<12;j++){
    const int c = (cl<<2) + (j<<6);
    float4 w4[4];
#pragma unroll
    for (int k=0;k<4;k++){
      const int v = vbase + 4*k;
      if (v < Vz) w4[k] = *(const float4*)(wte + (size_t)v*Ez + c);
      else { w4[k].x=w4[k].y=w4[k].z=w4[k].w=0.f; }
    }
#pragma unroll
    for (int b=0;b<16;b++){
      const float4 hv = *(const float4*)(&sLn[b][c]);
#pragma unroll
      for (int k=0;k<4;k++) acc[k][b] = dot4acc(acc[k][b], w4[k], hv);
    }
  }
#pragma unroll
  for (int off=1; off<16; off<<=1)
#pragma unroll
    for (int k=0;k<4;k++)
#pragma unroll
      for (int b=0;b<16;b++) acc[k][b] += __shfl_xor(acc[k][b], off);

  if (cl==0){
#pragma unroll
    for (int k=0;k<4;k++){
      const int v = vbase + 4*k;
      if (v < Vz){
#pragma unroll
        for (int b=0;b<16;b++) out[(size_t)b*Vz + v] = acc[k][b];
      }
    }
  }
}

extern "C" void kernel_launch(void* const* d_in, const int* in_sizes, int n_in,
                              void* d_out, int out_size, void* d_ws, size_t ws_size,
                              hipStream_t stream) {
  const int*   idx = (const int*)  d_in[0];
  const float* wte = (const float*)d_in[1];
  const float* Wih = (const float*)d_in[2];
  const float* bih = (const float*)d_in[3];
  const float* Whh = (const float*)d_in[4];
  const float* bhh = (const float*)d_in[5];
  const float* g   = (const float*)d_in[6];
  float* out = (float*)d_out;

  float* base = (float*)d_ws;
  unsigned* cnt = (unsigned*)d_ws;           // 32 counters at word offsets 0,32,...,992
  float* h0g = base + 1024;                  // 2 * B*E
  float* h1g = h0g + 2*VEC;                  // 2 * B*E
  float* ln  = h1g + 2*VEC;                  // B*E

  (void)hipMemsetAsync(d_ws, 0, 4096, stream);  // reset all counters each (re)play

  void* args[] = {(void*)&idx,(void*)&wte,(void*)&Wih,(void*)&bih,
                  (void*)&Whh,(void*)&bhh,(void*)&h0g,(void*)&h1g,(void*)&cnt};
  (void)hipLaunchCooperativeKernel((void*)gru_scan, dim3(NBK), dim3(256), args, 0, stream);

  // final h1(1023) lives in h1g[(Tz-1)&1] = h1g + VEC
  finalize_ln<<<1, 256, 0, stream>>>(h1g + VEC, g, ln);
  lm_head<<<786, 256, 0, stream>>>(ln, wte, out);
}

// Round 7
// 32589.185 us; speedup vs baseline: 1.3292x; 1.0291x over previous
//
#include <hip/hip_runtime.h>
#include <math.h>

#define Bz 16
#define Tz 1024
#define Ez 768
#define E3 2304
#define Vz 50257
#define NBK 256          // 256 blocks: 128 layer-0, 128 layer-1, 6 columns each
#define LN_EPS 1e-5f
#define VEC (Bz*Ez)      // 12288 floats per h vector
#define EP 772           // padded LDS row stride

__device__ __forceinline__ float dot4acc(float acc, float4 w, float4 h){
  acc = fmaf(w.x,h.x,acc); acc = fmaf(w.y,h.y,acc);
  acc = fmaf(w.z,h.z,acc); acc = fmaf(w.w,h.w,acc);
  return acc;
}
__device__ __forceinline__ float sigm(float x){ return 1.0f/(1.0f+expf(-x)); }

// ---------------------------------------------------------------------------
// Persistent cooperative scan; layer-skewed (L0 computes h0(s), L1 computes
// h1(s-1) in super-step s). Two-level STORE-ONLY barrier:
//   arrive:   flags[bx] = s+1   (256 distinct words -> no RMW, no ownership
//             bouncing; stores pipeline)
//   aggregate: block 0 wave 0 polls all 256 flags (64 lanes x 4 words),
//             then stores go = s (single writer)
//   wait:     all other blocks poll ONLY the clean `go` line with tid==0.
// Poll reads never mix with RMWs on the same line -> no slice-queueing storm.
// All accesses relaxed agent scope (sc1, L3-coherent); h-data visibility is
// by physical causality: h stores are vmcnt-drained (to L3) before the flag
// store issues. Weights stay L2-resident (no acquire -> no buffer_inv).
// ---------------------------------------------------------------------------
__global__ __launch_bounds__(256) void gru_scan(
    const int* __restrict__ idx, const float* __restrict__ wte,
    const float* __restrict__ Wih, const float* __restrict__ bih,
    const float* __restrict__ Whh, const float* __restrict__ bhh,
    float* __restrict__ h0g, float* __restrict__ h1g,
    unsigned* __restrict__ flags, unsigned* __restrict__ go)
{
  __shared__ float bufX0[Bz][EP];   // L0: x(t) ping   | L1: h0(t)
  __shared__ float bufX1[Bz][EP];   // L0: x(t) pong   | L1: unused
  __shared__ float bufH [Bz][EP];   // h_prev (own layer)
  __shared__ float gates[36][17];   // [row m][batch]
  __shared__ float biasS[36];

  const int tid = threadIdx.x, bx = blockIdx.x;
  const int L = bx>>7, sub = bx&127, c0 = sub*6;
  const int wv = tid>>6, lane = tid&63, kq = lane&15, bb = lane>>4;

  const float* WihL = Wih + (size_t)L*E3*Ez;
  const float* WhhL = Whh + (size_t)L*E3*Ez;

  // 9 weight-row pointers per wave. m = wv*9+r in [0,36):
  //  m<18 -> Wih rows (input = bufX), m>=18 -> Whh rows (input = bufH)
  const float* wrow[9];
#pragma unroll
  for (int r=0;r<9;r++){
    const int m = wv*9+r, mat = m/18, mm = m%18, g = mm/6, cc = mm-g*6;
    wrow[r] = (mat ? WhhL : WihL) + (size_t)(g*Ez + c0 + cc)*Ez;
  }
  if (tid<36){
    const int mat = tid/18, mm = tid%18, g = mm/6, cc = mm-g*6;
    biasS[tid] = (mat ? bhh : bih)[L*E3 + g*Ez + c0 + cc];
  }

  // preload x(0) for layer 0
  if (L==0){
#pragma unroll
    for (int k4=0;k4<12;k4++){
      const int i4 = tid + (k4<<8);
      const int b = i4/192, c4 = i4 - b*192;
      const int row = idx[b*Tz];
      *(float4*)&bufX0[b][c4<<2] = *(const float4*)(wte + (size_t)row*Ez + (c4<<2));
    }
  }
  __syncthreads();

  for (int s=0; s<=Tz; ++s){
    // ---- grid wait ----
    if (s>0){
      const unsigned tgt = (unsigned)s;
      if (bx==0){
        if (tid<64){
          const unsigned* f = flags + (tid<<2);
          for(;;){
            const unsigned a0 = __hip_atomic_load(f+0, __ATOMIC_RELAXED, __HIP_MEMORY_SCOPE_AGENT);
            const unsigned a1 = __hip_atomic_load(f+1, __ATOMIC_RELAXED, __HIP_MEMORY_SCOPE_AGENT);
            const unsigned a2 = __hip_atomic_load(f+2, __ATOMIC_RELAXED, __HIP_MEMORY_SCOPE_AGENT);
            const unsigned a3 = __hip_atomic_load(f+3, __ATOMIC_RELAXED, __HIP_MEMORY_SCOPE_AGENT);
            const int ok = (a0>=tgt) & (a1>=tgt) & (a2>=tgt) & (a3>=tgt);
            if (__all(ok)) break;
            __builtin_amdgcn_s_sleep(1);
          }
          if (tid==0)
            __hip_atomic_store(go, tgt, __ATOMIC_RELAXED, __HIP_MEMORY_SCOPE_AGENT);
        }
      } else {
        if (tid==0){
          while (__hip_atomic_load(go, __ATOMIC_RELAXED, __HIP_MEMORY_SCOPE_AGENT) < tgt)
            __builtin_amdgcn_s_sleep(1);
        }
      }
      __syncthreads();
    }

    const bool active = (L==0) ? (s<Tz) : (s>0);
    if (active){
      const int t = (L==0) ? s : s-1;

      // ---- stage phase: bypass-read h vectors into LDS ----
      if (L==0){
        if (t==0){
#pragma unroll
          for (int k=0;k<48;k++) bufH[k/3][tid + ((k%3)<<8)] = 0.f;
        } else {
          const float* hp = h0g + (size_t)((s-1)&1)*VEC;
#pragma unroll
          for (int k=0;k<48;k++){
            const float v = __hip_atomic_load(hp + tid + (k<<8),
                              __ATOMIC_RELAXED, __HIP_MEMORY_SCOPE_AGENT);
            bufH[k/3][tid + ((k%3)<<8)] = v;
          }
        }
      } else {
        const float* xp = h0g + (size_t)((s-1)&1)*VEC;   // h0(t)
#pragma unroll
        for (int k=0;k<48;k++){
          const float v = __hip_atomic_load(xp + tid + (k<<8),
                            __ATOMIC_RELAXED, __HIP_MEMORY_SCOPE_AGENT);
          bufX0[k/3][tid + ((k%3)<<8)] = v;
        }
        if (t==0){
#pragma unroll
          for (int k=0;k<48;k++) bufH[k/3][tid + ((k%3)<<8)] = 0.f;
        } else {
          const float* hp = h1g + (size_t)(s&1)*VEC;     // h1(t-1)
#pragma unroll
          for (int k=0;k<48;k++){
            const float v = __hip_atomic_load(hp + tid + (k<<8),
                              __ATOMIC_RELAXED, __HIP_MEMORY_SCOPE_AGENT);
            bufH[k/3][tid + ((k%3)<<8)] = v;
          }
        }
      }
      __syncthreads();

      // ---- matmul: 9 rows/wave x 16 batches, k split 16-way (kq) ----
      const float (*V)[EP];
      if (wv<2) V = (L==0) ? ((s&1) ? bufX1 : bufX0) : bufX0;
      else      V = bufH;

      float acc[9][4];
#pragma unroll
      for (int r=0;r<9;r++)
#pragma unroll
        for (int bi=0;bi<4;bi++) acc[r][bi]=0.f;

#pragma unroll 4
      for (int j=0;j<12;j++){
        const int kk = (j<<6) + (kq<<2);
        float4 wv4[9];
#pragma unroll
        for (int r=0;r<9;r++) wv4[r] = *(const float4*)(wrow[r] + kk);
#pragma unroll
        for (int bi=0;bi<4;bi++){
          const float4 hv = *(const float4*)&V[bb*4+bi][kk];
#pragma unroll
          for (int r=0;r<9;r++) acc[r][bi] = dot4acc(acc[r][bi], wv4[r], hv);
        }
      }
#pragma unroll
      for (int r=0;r<9;r++)
#pragma unroll
        for (int bi=0;bi<4;bi++){
          float a = acc[r][bi];
          a += __shfl_xor(a,1); a += __shfl_xor(a,2);
          a += __shfl_xor(a,4); a += __shfl_xor(a,8);
          acc[r][bi]=a;
        }
      if (kq==0){
#pragma unroll
        for (int r=0;r<9;r++)
#pragma unroll
          for (int bi=0;bi<4;bi++) gates[wv*9+r][bb*4+bi] = acc[r][bi];
      }
      __syncthreads();

      // ---- nonlinearity + publish h-slice (96 threads: 16 b x 6 cols) ----
      if (tid < 96){
        const int b = tid&15, cc = tid>>4;
        const float gir = gates[cc   ][b] + biasS[cc];
        const float giz = gates[6+cc ][b] + biasS[6+cc];
        const float gin = gates[12+cc][b] + biasS[12+cc];
        const float ghr = gates[18+cc][b] + biasS[18+cc];
        const float ghz = gates[24+cc][b] + biasS[24+cc];
        const float ghn = gates[30+cc][b] + biasS[30+cc];
        const float r = sigm(gir+ghr);
        const float z = sigm(giz+ghz);
        const float n = tanhf(fmaf(r, ghn, gin));
        const float hp = bufH[b][c0+cc];
        const float hv = fmaf(z, hp - n, n);
        float* hOut = (L==0) ? (h0g + (size_t)(s&1)*VEC)
                             : (h1g + (size_t)((s-1)&1)*VEC);
        __hip_atomic_store(hOut + b*Ez + c0 + cc, hv,
                           __ATOMIC_RELAXED, __HIP_MEMORY_SCOPE_AGENT);
      }
    }

    // ---- arrive: syncthreads drains vmcnt (h stores at L3), then flag ----
    __syncthreads();
    if (tid==0)
      __hip_atomic_store(flags + bx, (unsigned)(s+1),
                         __ATOMIC_RELAXED, __HIP_MEMORY_SCOPE_AGENT);

    // ---- prefetch x(s+1) AFTER arrive (off the barrier critical path) ----
    if (L==0 && active && s+1 < Tz){
      float (*bx_)[EP] = ((s+1)&1) ? bufX1 : bufX0;
#pragma unroll
      for (int k4=0;k4<12;k4++){
        const int i4 = tid + (k4<<8);
        const int b = i4/192, c4 = i4 - b*192;
        const int row = idx[b*Tz + (s+1)];
        *(float4*)&bx_[b][c4<<2] = *(const float4*)(wte + (size_t)row*Ez + (c4<<2));
      }
    }
  }
}

// LayerNorm of final h1 -> ln
__global__ __launch_bounds__(256) void finalize_ln(
    const float* __restrict__ h1, const float* __restrict__ g,
    float* __restrict__ ln)
{
  const int tid=threadIdx.x, wv=tid>>6, lane=tid&63;
  for (int b=wv; b<Bz; b+=4){
    float sum=0.f;
    for (int c=lane;c<Ez;c+=64) sum += h1[b*Ez+c];
#pragma unroll
    for (int off=32; off; off>>=1) sum += __shfl_xor(sum, off);
    const float mu = sum/(float)Ez;
    float s2=0.f;
    for (int c=lane;c<Ez;c+=64){ const float d=h1[b*Ez+c]-mu; s2=fmaf(d,d,s2); }
#pragma unroll
    for (int off=32; off; off>>=1) s2 += __shfl_xor(s2, off);
    const float inv = rsqrtf(s2/(float)Ez + LN_EPS);
    for (int c=lane;c<Ez;c+=64) ln[b*Ez+c] = (h1[b*Ez+c]-mu)*inv*g[c];
  }
}

// logits[b,v] = dot(ln[b,:], wte[v,:]) ; 64 rows per block, 16 rows per wave.
__global__ __launch_bounds__(256) void lm_head(
    const float* __restrict__ ln, const float* __restrict__ wte,
    float* __restrict__ out)
{
  __shared__ float sLn[Bz][EP];
  const int tid=threadIdx.x;
  for (int i4=tid; i4<Bz*Ez/4; i4+=256){
    const int b = i4/(Ez/4), c = (i4 - b*(Ez/4))<<2;
    *(float4*)(&sLn[b][c]) = *(const float4*)(ln + b*Ez + c);
  }
  __syncthreads();
  const int wv=tid>>6, lane=tid&63, rr=lane>>4, cl=lane&15;
  const int vbase = blockIdx.x*64 + wv*16 + rr;
  float acc[4][16];
#pragma unroll
  for (int k=0;k<4;k++)
#pragma unroll
    for (int b=0;b<16;b++) acc[k][b]=0.f;

  for (int j=0;j<12;j++){
    const int c = (cl<<2) + (j<<6);
    float4 w4[4];
#pragma unroll
    for (int k=0;k<4;k++){
      const int v = vbase + 4*k;
      if (v < Vz) w4[k] = *(const float4*)(wte + (size_t)v*Ez + c);
      else { w4[k].x=w4[k].y=w4[k].z=w4[k].w=0.f; }
    }
#pragma unroll
    for (int b=0;b<16;b++){
      const float4 hv = *(const float4*)(&sLn[b][c]);
#pragma unroll
      for (int k=0;k<4;k++) acc[k][b] = dot4acc(acc[k][b], w4[k], hv);
    }
  }
#pragma unroll
  for (int off=1; off<16; off<<=1)
#pragma unroll
    for (int k=0;k<4;k++)
#pragma unroll
      for (int b=0;b<16;b++) acc[k][b] += __shfl_xor(acc[k][b], off);

  if (cl==0){
#pragma unroll
    for (int k=0;k<4;k++){
      const int v = vbase + 4*k;
      if (v < Vz){
#pragma unroll
        for (int b=0;b<16;b++) out[(size_t)b*Vz + v] = acc[k][b];
      }
    }
  }
}

extern "C" void kernel_launch(void* const* d_in, const int* in_sizes, int n_in,
                              void* d_out, int out_size, void* d_ws, size_t ws_size,
                              hipStream_t stream) {
  const int*   idx = (const int*)  d_in[0];
  const float* wte = (const float*)d_in[1];
  const float* Wih = (const float*)d_in[2];
  const float* bih = (const float*)d_in[3];
  const float* Whh = (const float*)d_in[4];
  const float* bhh = (const float*)d_in[5];
  const float* g   = (const float*)d_in[6];
  float* out = (float*)d_out;

  float* base = (float*)d_ws;
  unsigned* flags = (unsigned*)d_ws;         // words [0,256): per-block flags
  unsigned* go    = (unsigned*)d_ws + 512;   // word 512: the broadcast word
  float* h0g = base + 1024;                  // 2 * B*E
  float* h1g = h0g + 2*VEC;                  // 2 * B*E
  float* ln  = h1g + 2*VEC;                  // B*E

  (void)hipMemsetAsync(d_ws, 0, 4096, stream);  // reset flags+go each (re)play

  void* args[] = {(void*)&idx,(void*)&wte,(void*)&Wih,(void*)&bih,
                  (void*)&Whh,(void*)&bhh,(void*)&h0g,(void*)&h1g,
                  (void*)&flags,(void*)&go};
  (void)hipLaunchCooperativeKernel((void*)gru_scan, dim3(NBK), dim3(256), args, 0, stream);

  // final h1(1023) lives in h1g[(Tz-1)&1] = h1g + VEC
  finalize_ln<<<1, 256, 0, stream>>>(h1g + VEC, g, ln);
  lm_head<<<786, 256, 0, stream>>>(ln, wte, out);
}

// Round 12
// 24485.840 us; speedup vs baseline: 1.7690x; 1.3309x over previous
//
#include <hip/hip_runtime.h>
#include <math.h>

#define Bz 16
#define Tz 1024
#define Ez 768
#define E3 2304
#define Vz 50257
#define NBK 256          // 256 blocks: 128 layer-0, 128 layer-1, 6 columns each
#define LN_EPS 1e-5f
#define VEC (Bz*Ez)      // 12288 floats per h vector
#define EP 772           // padded LDS row stride

__device__ __forceinline__ float dot4acc(float acc, float4 w, float4 h){
  acc = fmaf(w.x,h.x,acc); acc = fmaf(w.y,h.y,acc);
  acc = fmaf(w.z,h.z,acc); acc = fmaf(w.w,h.w,acc);
  return acc;
}
__device__ __forceinline__ float sigm(float x){ return 1.0f/(1.0f+expf(-x)); }

// ---- Staging: ONLY the proven-safe pattern (scalar 32-bit relaxed atomic
// load feeding an immediate LDS store), shortened by 2-wide interleave and
// 512-thread distribution. 5 rounds proved every batched/asm/DMA variant
// breaks (all-zero signature); do not widen beyond 2 loads per body. ----

// One 12288-float vector -> dst, 512 threads, 24 elems/thread as 12 bodies
// of 2 independent streams (u, u+6144): both loads in flight per round-trip.
__device__ __forceinline__ void stage_one(const float* __restrict__ src,
                                          float (*dst)[EP], int tid){
#pragma unroll
  for (int k=0;k<12;k++){
    const int u0 = tid + (k<<9);
    const int u1 = u0 + 6144;
    const float a = __hip_atomic_load(src+u0, __ATOMIC_RELAXED, __HIP_MEMORY_SCOPE_AGENT);
    const float b = __hip_atomic_load(src+u1, __ATOMIC_RELAXED, __HIP_MEMORY_SCOPE_AGENT);
    const int b0 = u0/768, c0_ = u0 - b0*768;
    const int b1 = u1/768, c1_ = u1 - b1*768;
    dst[b0][c0_] = a;
    dst[b1][c1_] = b;
  }
}

// Two vectors -> two buffers, interleaved (x[i], h[i] per body): 24 bodies.
__device__ __forceinline__ void stage_two(const float* __restrict__ srcX,
                                          float (*dstX)[EP],
                                          const float* __restrict__ srcH,
                                          float (*dstH)[EP], int tid){
#pragma unroll
  for (int k=0;k<24;k++){
    const int u = tid + (k<<9);
    const float a = __hip_atomic_load(srcX+u, __ATOMIC_RELAXED, __HIP_MEMORY_SCOPE_AGENT);
    const float b = __hip_atomic_load(srcH+u, __ATOMIC_RELAXED, __HIP_MEMORY_SCOPE_AGENT);
    const int bb_ = u/768, cc_ = u - bb_*768;
    dstX[bb_][cc_] = a;
    dstH[bb_][cc_] = b;
  }
}

__device__ __forceinline__ void zero_buf(float (*dst)[EP], int tid){
#pragma unroll
  for (int k=0;k<24;k++){
    const int u = tid + (k<<9);
    const int b = u/768, c = u - b*768;
    dst[b][c] = 0.f;
  }
}

// ---------------------------------------------------------------------------
// Persistent cooperative scan; layer-skewed (L0 computes h0(s), L1 computes
// h1(s-1) in super-step s). Two-level STORE-ONLY barrier (proven R7):
//   arrive: flags[bx]=s+1 ; block 0 aggregates -> go=s ; others poll go.
// All atomics 32-bit relaxed agent scope; publish stores vmcnt-drained by
// the pre-barrier syncthreads before the flag store.
// THIS ROUND: 512 threads/block (staging distribution only; matmul/publish
// still on tid<256, byte-identical to R7) + 2-wide interleaved staging.
// Serial chain/thread: 96 -> 24 round-trips.
// ---------------------------------------------------------------------------
__global__ __launch_bounds__(512) void gru_scan(
    const int* __restrict__ idx, const float* __restrict__ wte,
    const float* __restrict__ Wih, const float* __restrict__ bih,
    const float* __restrict__ Whh, const float* __restrict__ bhh,
    float* __restrict__ h0g, float* __restrict__ h1g,
    unsigned* __restrict__ flags, unsigned* __restrict__ go)
{
  __shared__ float bufX0[Bz][EP];   // L0: x(t) ping   | L1: h0(t)
  __shared__ float bufX1[Bz][EP];   // L0: x(t) pong   | L1: unused
  __shared__ float bufH [Bz][EP];   // h_prev (own layer)
  __shared__ float gates[36][17];   // [row m][batch]
  __shared__ float biasS[36];

  const int tid = threadIdx.x, bx = blockIdx.x;
  const int L = bx>>7, sub = bx&127, c0 = sub*6;
  const int wv = tid>>6, lane = tid&63, kq = lane&15, bb = lane>>4;

  const float* WihL = Wih + (size_t)L*E3*Ez;
  const float* WhhL = Whh + (size_t)L*E3*Ez;

  // 9 weight-row pointers per wave (meaningful for tid<256 / wv<4 only).
  const float* wrow[9];
#pragma unroll
  for (int r=0;r<9;r++){
    const int m = (wv&3)*9+r, mat = m/18, mm = m%18, g = mm/6, cc = mm-g*6;
    wrow[r] = (mat ? WhhL : WihL) + (size_t)(g*Ez + c0 + cc)*Ez;
  }
  if (tid<36){
    const int mat = tid/18, mm = tid%18, g = mm/6, cc = mm-g*6;
    biasS[tid] = (mat ? bhh : bih)[L*E3 + g*Ez + c0 + cc];
  }

  // preload x(0) for layer 0 (512 threads x 6 float4)
  if (L==0){
#pragma unroll
    for (int k4=0;k4<6;k4++){
      const int i4 = tid + (k4<<9);
      const int b = i4/192, c4 = i4 - b*192;
      const int row = idx[b*Tz];
      *(float4*)&bufX0[b][c4<<2] = *(const float4*)(wte + (size_t)row*Ez + (c4<<2));
    }
  }
  __syncthreads();

  for (int s=0; s<=Tz; ++s){
    // ---- grid wait ----
    if (s>0){
      const unsigned tgt = (unsigned)s;
      if (bx==0){
        if (tid<64){
          const unsigned* f = flags + (tid<<2);
          for(;;){
            const unsigned a0 = __hip_atomic_load(f+0, __ATOMIC_RELAXED, __HIP_MEMORY_SCOPE_AGENT);
            const unsigned a1 = __hip_atomic_load(f+1, __ATOMIC_RELAXED, __HIP_MEMORY_SCOPE_AGENT);
            const unsigned a2 = __hip_atomic_load(f+2, __ATOMIC_RELAXED, __HIP_MEMORY_SCOPE_AGENT);
            const unsigned a3 = __hip_atomic_load(f+3, __ATOMIC_RELAXED, __HIP_MEMORY_SCOPE_AGENT);
            const int ok = (a0>=tgt) & (a1>=tgt) & (a2>=tgt) & (a3>=tgt);
            if (__all(ok)) break;
            __builtin_amdgcn_s_sleep(1);
          }
          if (tid==0)
            __hip_atomic_store(go, tgt, __ATOMIC_RELAXED, __HIP_MEMORY_SCOPE_AGENT);
        }
      } else {
        if (tid==0){
          while (__hip_atomic_load(go, __ATOMIC_RELAXED, __HIP_MEMORY_SCOPE_AGENT) < tgt)
            __builtin_amdgcn_s_sleep(1);
        }
      }
      __syncthreads();
    }

    const bool active = (L==0) ? (s<Tz) : (s>0);
    if (active){
      const int t = (L==0) ? s : s-1;

      // ---- stage phase (512 threads, 2-wide interleaved scalar UC) ----
      if (L==0){
        if (t==0) zero_buf(bufH, tid);
        else      stage_one(h0g + (size_t)((s-1)&1)*VEC, bufH, tid);
      } else {
        if (t==0){
          stage_one(h0g + (size_t)((s-1)&1)*VEC, bufX0, tid);
          zero_buf(bufH, tid);
        } else {
          stage_two(h0g + (size_t)((s-1)&1)*VEC, bufX0,
                    h1g + (size_t)(s&1)*VEC,     bufH, tid);
        }
      }
      __syncthreads();

      // ---- matmul on waves 0-3 only (byte-identical to R7) ----
      if (tid < 256){
        const float (*V)[EP];
        if (wv<2) V = (L==0) ? ((s&1) ? bufX1 : bufX0) : bufX0;
        else      V = bufH;

        float acc[9][4];
#pragma unroll
        for (int r=0;r<9;r++)
#pragma unroll
          for (int bi=0;bi<4;bi++) acc[r][bi]=0.f;

#pragma unroll 4
        for (int j=0;j<12;j++){
          const int kk = (j<<6) + (kq<<2);
          float4 wv4[9];
#pragma unroll
          for (int r=0;r<9;r++) wv4[r] = *(const float4*)(wrow[r] + kk);
#pragma unroll
          for (int bi=0;bi<4;bi++){
            const float4 hv = *(const float4*)&V[bb*4+bi][kk];
#pragma unroll
            for (int r=0;r<9;r++) acc[r][bi] = dot4acc(acc[r][bi], wv4[r], hv);
          }
        }
#pragma unroll
        for (int r=0;r<9;r++)
#pragma unroll
          for (int bi=0;bi<4;bi++){
            float a = acc[r][bi];
            a += __shfl_xor(a,1); a += __shfl_xor(a,2);
            a += __shfl_xor(a,4); a += __shfl_xor(a,8);
            acc[r][bi]=a;
          }
        if (kq==0){
#pragma unroll
          for (int r=0;r<9;r++)
#pragma unroll
            for (int bi=0;bi<4;bi++) gates[wv*9+r][bb*4+bi] = acc[r][bi];
        }
      }
      __syncthreads();

      // ---- nonlinearity + publish h-slice (96 threads: 16 b x 6 cols) ----
      if (tid < 96){
        const int b = tid&15, cc = tid>>4;
        const float gir = gates[cc   ][b] + biasS[cc];
        const float giz = gates[6+cc ][b] + biasS[6+cc];
        const float gin = gates[12+cc][b] + biasS[12+cc];
        const float ghr = gates[18+cc][b] + biasS[18+cc];
        const float ghz = gates[24+cc][b] + biasS[24+cc];
        const float ghn = gates[30+cc][b] + biasS[30+cc];
        const float r = sigm(gir+ghr);
        const float z = sigm(giz+ghz);
        const float n = tanhf(fmaf(r, ghn, gin));
        const float hp = bufH[b][c0+cc];
        const float hv = fmaf(z, hp - n, n);
        float* hOut = (L==0) ? (h0g + (size_t)(s&1)*VEC)
                             : (h1g + (size_t)((s-1)&1)*VEC);
        __hip_atomic_store(hOut + b*Ez + c0 + cc, hv,
                           __ATOMIC_RELAXED, __HIP_MEMORY_SCOPE_AGENT);
      }
    }

    // ---- arrive: syncthreads drains vmcnt (h stores at L3), then flag ----
    __syncthreads();
    if (tid==0)
      __hip_atomic_store(flags + bx, (unsigned)(s+1),
                         __ATOMIC_RELAXED, __HIP_MEMORY_SCOPE_AGENT);

    // ---- prefetch x(s+1) AFTER arrive (off the barrier critical path) ----
    if (L==0 && active && s+1 < Tz){
      float (*bx_)[EP] = ((s+1)&1) ? bufX1 : bufX0;
#pragma unroll
      for (int k4=0;k4<6;k4++){
        const int i4 = tid + (k4<<9);
        const int b = i4/192, c4 = i4 - b*192;
        const int row = idx[b*Tz + (s+1)];
        *(float4*)&bx_[b][c4<<2] = *(const float4*)(wte + (size_t)row*Ez + (c4<<2));
      }
    }
  }
}

// LayerNorm of final h1 -> ln
__global__ __launch_bounds__(256) void finalize_ln(
    const float* __restrict__ h1, const float* __restrict__ g,
    float* __restrict__ ln)
{
  const int tid=threadIdx.x, wv=tid>>6, lane=tid&63;
  for (int b=wv; b<Bz; b+=4){
    float sum=0.f;
    for (int c=lane;c<Ez;c+=64) sum += h1[b*Ez+c];
#pragma unroll
    for (int off=32; off; off>>=1) sum += __shfl_xor(sum, off);
    const float mu = sum/(float)Ez;
    float s2=0.f;
    for (int c=lane;c<Ez;c+=64){ const float d=h1[b*Ez+c]-mu; s2=fmaf(d,d,s2); }
#pragma unroll
    for (int off=32; off; off>>=1) s2 += __shfl_xor(s2, off);
    const float inv = rsqrtf(s2/(float)Ez + LN_EPS);
    for (int c=lane;c<Ez;c+=64) ln[b*Ez+c] = (h1[b*Ez+c]-mu)*inv*g[c];
  }
}

// logits[b,v] = dot(ln[b,:], wte[v,:]) ; 64 rows per block, 16 rows per wave.
__global__ __launch_bounds__(256) void lm_head(
    const float* __restrict__ ln, const float* __restrict__ wte,
    float* __restrict__ out)
{
  __shared__ float sLn[Bz][EP];
  const int tid=threadIdx.x;
  for (int i4=tid; i4<Bz*Ez/4; i4+=256){
    const int b = i4/(Ez/4), c = (i4 - b*(Ez/4))<<2;
    *(float4*)(&sLn[b][c]) = *(const float4*)(ln + b*Ez + c);
  }
  __syncthreads();
  const int wv=tid>>6, lane=tid&63, rr=lane>>4, cl=lane&15;
  const int vbase = blockIdx.x*64 + wv*16 + rr;
  float acc[4][16];
#pragma unroll
  for (int k=0;k<4;k++)
#pragma unroll
    for (int b=0;b<16;b++) acc[k][b]=0.f;

  for (int j=0;j<12;j++){
    const int c = (cl<<2) + (j<<6);
    float4 w4[4];
#pragma unroll
    for (int k=0;k<4;k++){
      const int v = vbase + 4*k;
      if (v < Vz) w4[k] = *(const float4*)(wte + (size_t)v*Ez + c);
      else { w4[k].x=w4[k].y=w4[k].z=w4[k].w=0.f; }
    }
#pragma unroll
    for (int b=0;b<16;b++){
      const float4 hv = *(const float4*)(&sLn[b][c]);
#pragma unroll
      for (int k=0;k<4;k++) acc[k][b] = dot4acc(acc[k][b], w4[k], hv);
    }
  }
#pragma unroll
  for (int off=1; off<16; off<<=1)
#pragma unroll
    for (int k=0;k<4;k++)
#pragma unroll
      for (int b=0;b<16;b++) acc[k][b] += __shfl_xor(acc[k][b], off);

  if (cl==0){
#pragma unroll
    for (int k=0;k<4;k++){
      const int v = vbase + 4*k;
      if (v < Vz){
#pragma unroll
        for (int b=0;b<16;b++) out[(size_t)b*Vz + v] = acc[k][b];
      }
    }
  }
}

extern "C" void kernel_launch(void* const* d_in, const int* in_sizes, int n_in,
                              void* d_out, int out_size, void* d_ws, size_t ws_size,
                              hipStream_t stream) {
  const int*   idx = (const int*)  d_in[0];
  const float* wte = (const float*)d_in[1];
  const float* Wih = (const float*)d_in[2];
  const float* bih = (const float*)d_in[3];
  const float* Whh = (const float*)d_in[4];
  const float* bhh = (const float*)d_in[5];
  const float* g   = (const float*)d_in[6];
  float* out = (float*)d_out;

  float* base = (float*)d_ws;
  unsigned* flags = (unsigned*)d_ws;         // words [0,256): per-block flags
  unsigned* go    = (unsigned*)d_ws + 512;   // word 512: the broadcast word
  float* h0g = base + 1024;                  // 2 * B*E
  float* h1g = h0g + 2*VEC;                  // 2 * B*E
  float* ln  = h1g + 2*VEC;                  // B*E

  (void)hipMemsetAsync(d_ws, 0, 4096, stream);  // reset flags+go each (re)play

  void* args[] = {(void*)&idx,(void*)&wte,(void*)&Wih,(void*)&bih,
                  (void*)&Whh,(void*)&bhh,(void*)&h0g,(void*)&h1g,
                  (void*)&flags,(void*)&go};
  (void)hipLaunchCooperativeKernel((void*)gru_scan, dim3(NBK), dim3(512), args, 0, stream);

  // final h1(1023) lives in h1g[(Tz-1)&1] = h1g + VEC
  finalize_ln<<<1, 256, 0, stream>>>(h1g + VEC, g, ln);
  lm_head<<<786, 256, 0, stream>>>(ln, wte, out);
}